// Round 7
// baseline (369.510 us; speedup 1.0000x reference)
//
#include <hip/hip_runtime.h>
#include <hip/hip_cooperative_groups.h>

typedef __bf16 bf16_t;
typedef __bf16 bf16x8 __attribute__((ext_vector_type(8)));
typedef float f32x4 __attribute__((ext_vector_type(4)));

#define MFMA_BF16(a, b, c) __builtin_amdgcn_mfma_f32_16x16x32_bf16((a), (b), (c), 0, 0, 0)

static constexpr int Bn = 4096;
static constexpr int Dn = 1024;
static constexpr int Rn = 256;
static constexpr int BT = 16;
static constexpr float DTv = 0.01f;
static constexpr float HDT = 0.005f;

// XOR-swizzle within a 1024-float row: flips bits [4:2] by bits [7:5]. Bijective,
// preserves 4-float (16B) contiguity, spreads stride-16-float access over bank-slots.
__device__ __forceinline__ int swz(int col) { return col ^ (((col >> 5) & 7) << 2); }

// ---- Single fused COOPERATIVE kernel: 256 blocks x 1024 thr, 1 block/CU ----
// (cooperative launch guarantees co-residency; grid.sync() replaces flag spin)
// Setup duties (before the grid sync):
//   blocks  0..31: pack U slice kb=b    -> Upk (coalesced via LDS)
//   blocks 32..39: pack W slice kb=b-32 -> Wpk (coalesced via LDS)
//   blocks 40..55: WU = W@U rows m*16   -> WUpk (raw-U B-ring, no Upk dep)
// All blocks: load x/v/f + stage abuf (independent of packed data), then grid.sync().
// Integrate math (exact identity vs the half-step recurrence):
//   hv_{h+1} = hv_h + hdt*(FU - T_h@WU),  FU = f@U, WU = W@U
//   v_out = v0 + s*dt*f - hdt*(S1@W),     S1 = sum T_h
//   x_out = x0 + s*dt*v0 + s^2*dt*hdt*f - dt*hdt*(S2@W),  S2 = sum c_h*T_h, c_h = s-ceil(h/2)
__global__ __launch_bounds__(1024)
__attribute__((amdgpu_waves_per_eu(4, 4)))
void fused_kernel(const float* __restrict__ x_in, const float* __restrict__ v_in,
                  const float* __restrict__ force,
                  const float* __restrict__ U, const float* __restrict__ W,
                  bf16_t* __restrict__ Upk, bf16_t* __restrict__ Wpk,
                  bf16_t* __restrict__ WUpk,
                  const int* __restrict__ steps_p, float* __restrict__ out) {
  // union: pack ubuf[32][268] / wbuf2[32][1044] (66816B) / WU wbuf[16][1032] (33KB)
  //        init abuf[3][16][1032] bf16 (99072B) / loop tbf[2][16][264] /
  //        final sbuf[2][16][264] / epilogue fsb[8][1024] f32 (32KB)
  __shared__ __align__(16) char smem[99072];
  bf16_t* abuf = (bf16_t*)smem;
  float* fsb = (float*)smem;

  const int tid = (int)threadIdx.x;
  const int b = (int)blockIdx.x;
  const int wv = tid >> 6;  // 0..15
  const int l = tid & 63;
  const int ln = l & 15;
  const int quad = l >> 4;
  const int s = steps_p[0];
  const int nhalf = 2 * s;
  const int row_base = b * BT;

  float* out_x = out;
  float* out_v = out + (size_t)Bn * Dn;

  // ================= setup duties (smem use ends before abuf staging) =================
  if (b < 32) {  // ---- pack U, kb = b: tile U[32 rows][256 cols] ----
    bf16_t* ubuf = (bf16_t*)smem;  // [32][268]
    const int row = tid >> 5, c0 = (tid & 31) * 8;
    const float* src = U + (size_t)(b * 32 + row) * Rn + c0;
    f32x4 u0 = *(const f32x4*)src;
    f32x4 u1 = *(const f32x4*)(src + 4);
    bf16_t* d = ubuf + row * 268 + c0;
#pragma unroll
    for (int j = 0; j < 4; ++j) { d[j] = (bf16_t)u0[j]; d[4 + j] = (bf16_t)u1[j]; }
    __syncthreads();
    bf16x8 v;  // wave wv emits ct = wv
#pragma unroll
    for (int j = 0; j < 8; ++j) v[j] = ubuf[(quad * 8 + j) * 268 + wv * 16 + ln];
    ((bf16x8*)Upk)[(size_t)(wv * 32 + b) * 64 + l] = v;
    __syncthreads();  // ubuf dead before abuf staging
  } else if (b < 40) {  // ---- pack W, kb = b-32: tile W[32 rows][1024 cols] ----
    const int kb = b - 32;
    bf16_t* wbuf2 = (bf16_t*)smem;  // [32][1044]
    const int row = tid >> 5, c0 = (tid & 31) * 32;
    const float* src = W + (size_t)(kb * 32 + row) * Dn + c0;
    bf16_t* d = wbuf2 + row * 1044 + c0;
#pragma unroll
    for (int k = 0; k < 8; ++k) {
      f32x4 u = *(const f32x4*)(src + k * 4);
#pragma unroll
      for (int j = 0; j < 4; ++j) d[k * 4 + j] = (bf16_t)u[j];
    }
    __syncthreads();
#pragma unroll
    for (int cc = 0; cc < 4; ++cc) {  // wave wv emits cts {wv, wv+16, wv+32, wv+48}
      const int ct = wv + cc * 16;
      bf16x8 v;
#pragma unroll
      for (int j = 0; j < 8; ++j) v[j] = wbuf2[(quad * 8 + j) * 1044 + ct * 16 + ln];
      ((bf16x8*)Wpk)[(size_t)(ct * 8 + kb) * 64 + l] = v;
    }
    __syncthreads();  // wbuf2 dead
  } else if (b < 56) {  // ---- WU = W @ U, rows m*16..+16; raw-U ring, no Upk dep ----
    const int m = b - 40;
    bf16_t* wbuf = (bf16_t*)smem;  // [16][1032]
    {
      int row = tid >> 6;
      int c0 = (tid & 63) * 16;
      const float* src = W + (size_t)(m * 16 + row) * Dn + c0;
      bf16_t* dst = wbuf + row * 1032 + c0;
#pragma unroll
      for (int j = 0; j < 16; ++j) dst[j] = (bf16_t)src[j];
    }
    __syncthreads();
    const int ucol = wv * 16 + ln;
    float uf[8][8];  // depth-8 ring, fully unrolled
#pragma unroll
    for (int p = 0; p < 8; ++p)
#pragma unroll
      for (int j = 0; j < 8; ++j)
        uf[p][j] = U[(size_t)(p * 32 + quad * 8 + j) * Rn + ucol];
    f32x4 acc = {0.f, 0.f, 0.f, 0.f};
    const bf16_t* arow = wbuf + ln * 1032 + quad * 8;
#pragma unroll
    for (int kb = 0; kb < 32; ++kb) {
      bf16x8 bb;
#pragma unroll
      for (int j = 0; j < 8; ++j) bb[j] = (bf16_t)uf[kb & 7][j];
      const bf16x8 a = *(const bf16x8*)(arow + kb * 32);
      acc = MFMA_BF16(a, bb, acc);
      if (kb < 24) {
#pragma unroll
        for (int j = 0; j < 8; ++j)
          uf[kb & 7][j] = U[(size_t)((kb + 8) * 32 + quad * 8 + j) * Rn + ucol];
      }
    }
#pragma unroll
    for (int r = 0; r < 4; ++r) {  // scatter to packed slots
      int rw = m * 16 + quad * 4 + r;
      int kb = rw >> 5;
      int sub = (rw >> 3) & 3;
      int j = rw & 7;
      size_t slot = ((size_t)(wv * 8 + kb) * 64 + sub * 16 + ln) * 8 + j;
      WUpk[slot] = (bf16_t)acc[r];
    }
    __syncthreads();  // wbuf dead before abuf reuse
  }

  // ================= per-block input load + staging (all blocks) =================
  float xs[4][4], vs[4][4];  // ORIGINAL x0, v0 (C/D layout)
  bf16_t fsv[4][4];

  // ---- direct C/D loads: 16 lanes x 64B contiguous per instr => line-perfect ----
#pragma unroll
  for (int i = 0; i < 4; ++i) {
    const int col = (wv * 4 + i) * 16 + ln;
#pragma unroll
    for (int r = 0; r < 4; ++r) {
      const size_t g = (size_t)(row_base + quad * 4 + r) * Dn + col;
      xs[i][r] = x_in[g];
      vs[i][r] = v_in[g];
      fsv[i][r] = (bf16_t)force[g];
    }
  }
  // ---- stage full-width abuf directly from regs ----
#pragma unroll
  for (int i = 0; i < 4; ++i) {
    const int col = (wv * 4 + i) * 16 + ln;
#pragma unroll
    for (int r = 0; r < 4; ++r) {
      const int ro = (quad * 4 + r) * 1032 + col;
      abuf[ro] = (bf16_t)xs[i][r];
      abuf[16512 + ro] = (bf16_t)vs[i][r];
      abuf[33024 + ro] = fsv[i][r];
    }
  }
  __threadfence();  // make pack stores globally visible before the grid barrier

  // ---- grid-wide barrier: all packed data ready, all abuf staged ----
  cooperative_groups::this_grid().sync();

  // ---- WU fragments (ct = wv) first: L2 latency hides under U-pass MFMAs ----
  bf16x8 wu[8];
  {
    const bf16x8* wub = (const bf16x8*)WUpk + (size_t)wv * 8 * 64 + l;
#pragma unroll
    for (int kb = 0; kb < 8; ++kb) wu[kb] = wub[kb * 64];
  }

  // ---- init: hx0 = x0@U, hv0 = v0@U, FU = f@U; ONE 32-deep Upk pass ----
  f32x4 hx = {0.f, 0.f, 0.f, 0.f};
  f32x4 hv = {0.f, 0.f, 0.f, 0.f};
  f32x4 FU = {0.f, 0.f, 0.f, 0.f};
  {
    const bf16x8* up = (const bf16x8*)Upk + (size_t)wv * 32 * 64 + l;
    const bf16_t* ax = abuf + ln * 1032 + quad * 8;
    bf16x8 ur[8];
#pragma unroll
    for (int p = 0; p < 8; ++p) ur[p] = up[p * 64];
#pragma unroll
    for (int kb = 0; kb < 32; ++kb) {
      const bf16x8 bb = ur[kb & 7];
      if (kb < 24) ur[kb & 7] = up[(kb + 8) * 64];
      const bf16x8 a0 = *(const bf16x8*)(ax + kb * 32);
      const bf16x8 a1 = *(const bf16x8*)(ax + 16512 + kb * 32);
      const bf16x8 a2 = *(const bf16x8*)(ax + 33024 + kb * 32);
      hx = MFMA_BF16(a0, bb, hx);
      hv = MFMA_BF16(a1, bb, hv);
      FU = MFMA_BF16(a2, bb, FU);
    }
  }
  __syncthreads();  // abuf dead

  // ---- R-space loop: zero global traffic; dbuf T, 1 barrier/half-step ----
  f32x4 S1 = {0.f, 0.f, 0.f, 0.f};
  f32x4 S2 = {0.f, 0.f, 0.f, 0.f};
  bf16_t* tbase = (bf16_t*)smem;
  for (int h = 0; h < nhalf; ++h) {
    if (h & 1) {
#pragma unroll
      for (int r = 0; r < 4; ++r) hx[r] += DTv * hv[r];
    }
    const float ch = (float)(s - ((h + 1) >> 1));
    bf16_t* tb = tbase + (h & 1) * 4224;
#pragma unroll
    for (int r = 0; r < 4; ++r) {
      float a = fminf(fmaxf(hx[r], -15.f), 15.f);
      const float e = __expf(2.f * a);
      const float gate = 1.f - 2.f * __builtin_amdgcn_rcpf(e + 1.f);  // tanh(a)
      const float t = gate * hv[r] * hv[r];
      S1[r] += t;
      S2[r] += ch * t;
      tb[(quad * 4 + r) * 264 + wv * 16 + ln] = (bf16_t)t;
    }
    __syncthreads();
    f32x4 g0 = {0.f, 0.f, 0.f, 0.f};
    f32x4 g1 = {0.f, 0.f, 0.f, 0.f};
    f32x4 g2 = {0.f, 0.f, 0.f, 0.f};
    f32x4 g3 = {0.f, 0.f, 0.f, 0.f};
    const bf16_t* trow = tb + ln * 264 + quad * 8;
    g0 = MFMA_BF16(*(const bf16x8*)(trow + 0 * 32), wu[0], g0);
    g1 = MFMA_BF16(*(const bf16x8*)(trow + 1 * 32), wu[1], g1);
    g2 = MFMA_BF16(*(const bf16x8*)(trow + 2 * 32), wu[2], g2);
    g3 = MFMA_BF16(*(const bf16x8*)(trow + 3 * 32), wu[3], g3);
    g0 = MFMA_BF16(*(const bf16x8*)(trow + 4 * 32), wu[4], g0);
    g1 = MFMA_BF16(*(const bf16x8*)(trow + 5 * 32), wu[5], g1);
    g2 = MFMA_BF16(*(const bf16x8*)(trow + 6 * 32), wu[6], g2);
    g3 = MFMA_BF16(*(const bf16x8*)(trow + 7 * 32), wu[7], g3);
#pragma unroll
    for (int r = 0; r < 4; ++r)
      hv[r] += HDT * (FU[r] - ((g0[r] + g1[r]) + (g2[r] + g3[r])));
    // no second barrier: next iteration writes the OTHER buffer
  }
  __syncthreads();  // all T reads done before sbuf overwrite

  // ---- final: G1 = S1@W, G2 = S2@W, one Wpk pass; depth-2 ring per stream ----
  bf16_t* sbuf = (bf16_t*)smem;
#pragma unroll
  for (int r = 0; r < 4; ++r) {
    const int ro = (quad * 4 + r) * 264 + wv * 16 + ln;
    sbuf[ro] = (bf16_t)S1[r];
    sbuf[4224 + ro] = (bf16_t)S2[r];
  }
  __syncthreads();
  f32x4 ac1[4], ac2[4];
#pragma unroll
  for (int i = 0; i < 4; ++i) {
    ac1[i] = (f32x4){0.f, 0.f, 0.f, 0.f};
    ac2[i] = (f32x4){0.f, 0.f, 0.f, 0.f};
  }
  {
    const bf16x8* wp = (const bf16x8*)Wpk + (size_t)(wv * 4) * 8 * 64 + l;
    const bf16_t* s1row = sbuf + ln * 264 + quad * 8;
    const bf16_t* s2row = s1row + 4224;
    bf16x8 wr[4][2];
#pragma unroll
    for (int i = 0; i < 4; ++i) {
      wr[i][0] = wp[i * 512];
      wr[i][1] = wp[i * 512 + 64];
    }
#pragma unroll
    for (int kb = 0; kb < 8; ++kb) {
      const bf16x8 a1 = *(const bf16x8*)(s1row + kb * 32);
      const bf16x8 a2 = *(const bf16x8*)(s2row + kb * 32);
#pragma unroll
      for (int i = 0; i < 4; ++i) {
        const bf16x8 bb = wr[i][kb & 1];
        if (kb < 6) wr[i][kb & 1] = wp[i * 512 + (kb + 2) * 64];
        ac1[i] = MFMA_BF16(a1, bb, ac1[i]);
        ac2[i] = MFMA_BF16(a2, bb, ac2[i]);
      }
    }
  }
  __syncthreads();  // sbuf reads done before fsb overwrite

  // ---- epilogue: closed form, lane-contiguous full-line stores via swizzled LDS ----
  const float sf = (float)s;
  const float c_vf = sf * DTv;
  const float c_xf = sf * sf * DTv * HDT;
  int csw[4];
#pragma unroll
  for (int i = 0; i < 4; ++i) csw[i] = swz((wv * 4 + i) * 16 + ln);
  auto store_chunk = [&](float* __restrict__ dstA, int HF, auto vex) {
    if ((quad >> 1) == HF) {
#pragma unroll
      for (int i = 0; i < 4; ++i)
#pragma unroll
        for (int r = 0; r < 4; ++r)
          fsb[((quad & 1) * 4 + r) * 1024 + csw[i]] = vex(i, r);
    }
    __syncthreads();
    float* dst_ = dstA + (size_t)(row_base + HF * 8) * Dn;
#pragma unroll
    for (int k = 0; k < 2; ++k) {
      const int fi = k * 4096 + tid * 4;
      *(f32x4*)(dst_ + fi) = *(const f32x4*)(fsb + (fi >> 10) * 1024 + swz(fi & 1023));
    }
    __syncthreads();
  };
  auto vval = [&](int i, int r) {
    return vs[i][r] + c_vf * (float)fsv[i][r] - HDT * ac1[i][r];
  };
  auto xval = [&](int i, int r) {
    return xs[i][r] + c_vf * vs[i][r] + c_xf * (float)fsv[i][r] - DTv * HDT * ac2[i][r];
  };
  store_chunk(out_v, 0, vval);
  store_chunk(out_v, 1, vval);
  store_chunk(out_x, 0, xval);
  store_chunk(out_x, 1, xval);
}

extern "C" void kernel_launch(void* const* d_in, const int* in_sizes, int n_in,
                              void* d_out, int out_size, void* d_ws, size_t ws_size,
                              hipStream_t stream) {
  const float* x = (const float*)d_in[0];
  const float* v = (const float*)d_in[1];
  const float* force = (const float*)d_in[2];
  const float* U = (const float*)d_in[3];
  const float* W = (const float*)d_in[4];
  const int* steps = (const int*)d_in[5];

  bf16_t* Upk = (bf16_t*)d_ws;                          // 512 KB
  bf16_t* Wpk = (bf16_t*)((char*)d_ws + 512 * 1024);    // 512 KB
  bf16_t* WUpk = (bf16_t*)((char*)d_ws + 1024 * 1024);  // 128 KB
  float* out_f = (float*)d_out;

  void* args[] = {(void*)&x, (void*)&v, (void*)&force, (void*)&U, (void*)&W,
                  (void*)&Upk, (void*)&Wpk, (void*)&WUpk, (void*)&steps, (void*)&out_f};
  hipLaunchCooperativeKernel((const void*)fused_kernel, dim3(Bn / BT), dim3(1024), args,
                             0, stream);
}

// Round 8
// 291.660 us; speedup vs baseline: 1.2669x; 1.2669x over previous
//
#include <hip/hip_runtime.h>

typedef __bf16 bf16_t;
typedef __bf16 bf16x8 __attribute__((ext_vector_type(8)));
typedef float f32x4 __attribute__((ext_vector_type(4)));

#define MFMA_BF16(a, b, c) __builtin_amdgcn_mfma_f32_16x16x32_bf16((a), (b), (c), 0, 0, 0)

static constexpr int Bn = 4096;
static constexpr int Dn = 1024;
static constexpr int Rn = 256;
static constexpr int BT = 8;   // rows per block (half an MFMA M-tile; rows duplicated)
static constexpr float DTv = 0.01f;
static constexpr float HDT = 0.005f;

// XOR-swizzle within a 1024-float row: flips bits [4:2] by bits [7:5]. Bijective,
// preserves 4-float (16B) contiguity, spreads stride-16-float access over bank-slots.
__device__ __forceinline__ int swz(int col) { return col ^ (((col >> 5) & 7) << 2); }

// ---- Fused setup (one launch, 56 blocks x 1024): same as R5 (verified) ----
// blocks 0..31: pack U (kb=b); 32..39: pack W (kb=b-32); 40..55: WU = W@U (m=b-40)
// Upk[((ct*32+kb)*64+l)*8+j] = U[kb*32+(l>>4)*8+j][ct*16+(l&15)]
// Wpk[((ct*8+kb)*64+l)*8+j]  = W[kb*32+(l>>4)*8+j][ct*16+(l&15)]
// WUpk same layout as Wpk for WU[256x256].
__global__ __launch_bounds__(1024)
void setup_kernel(const float* __restrict__ U, const float* __restrict__ W,
                  bf16_t* __restrict__ Upk, bf16_t* __restrict__ Wpk,
                  bf16_t* __restrict__ WUpk) {
  __shared__ __align__(16) char ssm[66816];
  const int tid = (int)threadIdx.x;
  const int b = (int)blockIdx.x;
  const int l = tid & 63;
  const int wv = tid >> 6;
  const int ln = l & 15;
  const int quad = l >> 4;

  if (b < 32) {  // ---- pack U, kb = b ----
    bf16_t* ubuf = (bf16_t*)ssm;  // [32][268]
    const int row = tid >> 5, c0 = (tid & 31) * 8;
    const float* src = U + (size_t)(b * 32 + row) * Rn + c0;
    f32x4 u0 = *(const f32x4*)src;
    f32x4 u1 = *(const f32x4*)(src + 4);
    bf16_t* d = ubuf + row * 268 + c0;
#pragma unroll
    for (int j = 0; j < 4; ++j) { d[j] = (bf16_t)u0[j]; d[4 + j] = (bf16_t)u1[j]; }
    __syncthreads();
    bf16x8 v;
#pragma unroll
    for (int j = 0; j < 8; ++j) v[j] = ubuf[(quad * 8 + j) * 268 + wv * 16 + ln];
    ((bf16x8*)Upk)[(size_t)(wv * 32 + b) * 64 + l] = v;
  } else if (b < 40) {  // ---- pack W, kb = b-32 ----
    const int kb = b - 32;
    bf16_t* wbuf2 = (bf16_t*)ssm;  // [32][1044]
    const int row = tid >> 5, c0 = (tid & 31) * 32;
    const float* src = W + (size_t)(kb * 32 + row) * Dn + c0;
    bf16_t* d = wbuf2 + row * 1044 + c0;
#pragma unroll
    for (int k = 0; k < 8; ++k) {
      f32x4 u = *(const f32x4*)(src + k * 4);
#pragma unroll
      for (int j = 0; j < 4; ++j) d[k * 4 + j] = (bf16_t)u[j];
    }
    __syncthreads();
#pragma unroll
    for (int cc = 0; cc < 4; ++cc) {
      const int ct = wv + cc * 16;
      bf16x8 v;
#pragma unroll
      for (int j = 0; j < 8; ++j) v[j] = wbuf2[(quad * 8 + j) * 1044 + ct * 16 + ln];
      ((bf16x8*)Wpk)[(size_t)(ct * 8 + kb) * 64 + l] = v;
    }
  } else {  // ---- WU = W @ U, rows m*16..+16 ----
    const int m = b - 40;
    bf16_t* wbuf = (bf16_t*)ssm;  // [16][1032]
    {
      int row = tid >> 6;
      int c0 = (tid & 63) * 16;
      const float* src = W + (size_t)(m * 16 + row) * Dn + c0;
      bf16_t* dst = wbuf + row * 1032 + c0;
#pragma unroll
      for (int j = 0; j < 16; ++j) dst[j] = (bf16_t)src[j];
    }
    __syncthreads();
    const int ucol = wv * 16 + ln;
    float uf[8][8];
#pragma unroll
    for (int p = 0; p < 8; ++p)
#pragma unroll
      for (int j = 0; j < 8; ++j)
        uf[p][j] = U[(size_t)(p * 32 + quad * 8 + j) * Rn + ucol];
    f32x4 acc = {0.f, 0.f, 0.f, 0.f};
    const bf16_t* arow = wbuf + ln * 1032 + quad * 8;
#pragma unroll
    for (int kb = 0; kb < 32; ++kb) {
      bf16x8 bb;
#pragma unroll
      for (int j = 0; j < 8; ++j) bb[j] = (bf16_t)uf[kb & 7][j];
      const bf16x8 a = *(const bf16x8*)(arow + kb * 32);
      acc = MFMA_BF16(a, bb, acc);
      if (kb < 24) {
#pragma unroll
        for (int j = 0; j < 8; ++j)
          uf[kb & 7][j] = U[(size_t)((kb + 8) * 32 + quad * 8 + j) * Rn + ucol];
      }
    }
#pragma unroll
    for (int r = 0; r < 4; ++r) {
      int rw = m * 16 + quad * 4 + r;
      int kb = rw >> 5;
      int sub = (rw >> 3) & 3;
      int j = rw & 7;
      size_t slot = ((size_t)(wv * 8 + kb) * 64 + sub * 16 + ln) * 8 + j;
      WUpk[slot] = (bf16_t)acc[r];
    }
  }
}

// ---- Fused integrator: 512 blocks x 1024 thr, BT=8 rows, 2 blocks/CU (32 waves) ----
// Two independent barrier domains per CU fill each other's phase bubbles.
// MFMA M=16 tiles carry duplicated rows: A-reads use (ln&7); quads 2-3 compute
// discarded duplicates. Valid data lives in quads 0-1 (C/D rows 0..7).
//   hv_{h+1} = hv_h + hdt*(FU - T_h@WU),  FU = f@U, WU = W@U
//   v_out = v0 + s*dt*f - hdt*(S1@W),     S1 = sum T_h
//   x_out = x0 + s*dt*v0 + s^2*dt*hdt*f - dt*hdt*(S2@W),  S2 = sum c_h*T_h, c_h = s-ceil(h/2)
__global__ __launch_bounds__(1024)
__attribute__((amdgpu_waves_per_eu(8, 8)))
void integrate_kernel(const float* __restrict__ x_in, const float* __restrict__ v_in,
                      const float* __restrict__ force,
                      const bf16_t* __restrict__ Upk, const bf16_t* __restrict__ Wpk,
                      const bf16_t* __restrict__ WUpk,
                      const int* __restrict__ steps_p, float* __restrict__ out) {
  // union: init abuf[3][8][1032] bf16 (49536B) / loop tbf[2][8][264] bf16 (8448B)
  //        / final sbuf[2][8][264] bf16 (8448B) / epilogue fsb[8][1024] f32 (32KB)
  __shared__ __align__(16) char smem[49536];
  bf16_t* abuf = (bf16_t*)smem;
  float* fsb = (float*)smem;

  const int tid = (int)threadIdx.x;
  const int wv = tid >> 6;  // 0..15
  const int l = tid & 63;
  const int ln = l & 15;
  const int quad = l >> 4;
  const int lv = quad < 2;  // lanes holding valid rows (C/D rows 0..7)
  const int s = steps_p[0];
  const int nhalf = 2 * s;
  const int row_base = (int)blockIdx.x * BT;

  float* out_x = out;
  float* out_v = out + (size_t)Bn * Dn;

  float xs[4][4], vs[4][4];  // ORIGINAL x0, v0 (C/D layout; valid in quads 0-1)
  bf16_t fsv[4][4];

  // ---- direct C/D loads (quads 0-1): 16 lanes x 64B contiguous => line-perfect ----
  if (lv) {
#pragma unroll
    for (int i = 0; i < 4; ++i) {
      const int col = (wv * 4 + i) * 16 + ln;
#pragma unroll
      for (int r = 0; r < 4; ++r) {
        const size_t g = (size_t)(row_base + quad * 4 + r) * Dn + col;
        xs[i][r] = x_in[g];
        vs[i][r] = v_in[g];
        fsv[i][r] = (bf16_t)force[g];
      }
    }
    // ---- stage abuf[3][8][1032] directly from regs ----
#pragma unroll
    for (int i = 0; i < 4; ++i) {
      const int col = (wv * 4 + i) * 16 + ln;
#pragma unroll
      for (int r = 0; r < 4; ++r) {
        const int ro = (quad * 4 + r) * 1032 + col;
        abuf[ro] = (bf16_t)xs[i][r];
        abuf[8256 + ro] = (bf16_t)vs[i][r];
        abuf[16512 + ro] = fsv[i][r];
      }
    }
  }
  __syncthreads();

  // ---- WU fragments (ct = wv) first: L2 latency hides under U-pass MFMAs ----
  bf16x8 wu[8];
  {
    const bf16x8* wub = (const bf16x8*)WUpk + (size_t)wv * 8 * 64 + l;
#pragma unroll
    for (int kb = 0; kb < 8; ++kb) wu[kb] = wub[kb * 64];
  }

  // ---- init: hx0 = x0@U, hv0 = v0@U, FU = f@U; ONE 32-deep Upk pass ----
  f32x4 hx = {0.f, 0.f, 0.f, 0.f};
  f32x4 hv = {0.f, 0.f, 0.f, 0.f};
  f32x4 FU = {0.f, 0.f, 0.f, 0.f};
  {
    const bf16x8* up = (const bf16x8*)Upk + (size_t)wv * 32 * 64 + l;
    const bf16_t* ax = abuf + (ln & 7) * 1032 + quad * 8;  // rows 8-15 duplicate 0-7
    bf16x8 ur[8];
#pragma unroll
    for (int p = 0; p < 8; ++p) ur[p] = up[p * 64];
#pragma unroll
    for (int kb = 0; kb < 32; ++kb) {
      const bf16x8 bb = ur[kb & 7];
      if (kb < 24) ur[kb & 7] = up[(kb + 8) * 64];
      const bf16x8 a0 = *(const bf16x8*)(ax + kb * 32);
      const bf16x8 a1 = *(const bf16x8*)(ax + 8256 + kb * 32);
      const bf16x8 a2 = *(const bf16x8*)(ax + 16512 + kb * 32);
      hx = MFMA_BF16(a0, bb, hx);
      hv = MFMA_BF16(a1, bb, hv);
      FU = MFMA_BF16(a2, bb, FU);
    }
  }
  __syncthreads();  // abuf dead

  // ---- R-space loop: zero global traffic; dbuf T[8][264], 1 barrier/half-step ----
  f32x4 S1 = {0.f, 0.f, 0.f, 0.f};
  f32x4 S2 = {0.f, 0.f, 0.f, 0.f};
  bf16_t* tbase = (bf16_t*)smem;
  for (int h = 0; h < nhalf; ++h) {
    if (h & 1) {
#pragma unroll
      for (int r = 0; r < 4; ++r) hx[r] += DTv * hv[r];
    }
    const float ch = (float)(s - ((h + 1) >> 1));
    bf16_t* tb = tbase + (h & 1) * 2112;
#pragma unroll
    for (int r = 0; r < 4; ++r) {
      float a = fminf(fmaxf(hx[r], -15.f), 15.f);
      const float e = __expf(2.f * a);
      const float gate = 1.f - 2.f * __builtin_amdgcn_rcpf(e + 1.f);  // tanh(a)
      const float t = gate * hv[r] * hv[r];
      S1[r] += t;
      S2[r] += ch * t;
      if (lv) tb[(quad * 4 + r) * 264 + wv * 16 + ln] = (bf16_t)t;
    }
    __syncthreads();
    f32x4 g0 = {0.f, 0.f, 0.f, 0.f};
    f32x4 g1 = {0.f, 0.f, 0.f, 0.f};
    f32x4 g2 = {0.f, 0.f, 0.f, 0.f};
    f32x4 g3 = {0.f, 0.f, 0.f, 0.f};
    const bf16_t* trow = tb + (ln & 7) * 264 + quad * 8;  // dup rows 8-15
    g0 = MFMA_BF16(*(const bf16x8*)(trow + 0 * 32), wu[0], g0);
    g1 = MFMA_BF16(*(const bf16x8*)(trow + 1 * 32), wu[1], g1);
    g2 = MFMA_BF16(*(const bf16x8*)(trow + 2 * 32), wu[2], g2);
    g3 = MFMA_BF16(*(const bf16x8*)(trow + 3 * 32), wu[3], g3);
    g0 = MFMA_BF16(*(const bf16x8*)(trow + 4 * 32), wu[4], g0);
    g1 = MFMA_BF16(*(const bf16x8*)(trow + 5 * 32), wu[5], g1);
    g2 = MFMA_BF16(*(const bf16x8*)(trow + 6 * 32), wu[6], g2);
    g3 = MFMA_BF16(*(const bf16x8*)(trow + 7 * 32), wu[7], g3);
#pragma unroll
    for (int r = 0; r < 4; ++r)
      hv[r] += HDT * (FU[r] - ((g0[r] + g1[r]) + (g2[r] + g3[r])));
    // no second barrier: next iteration writes the OTHER buffer
  }
  __syncthreads();  // all T reads done before sbuf overwrite

  // ---- final: G1 = S1@W, G2 = S2@W, one Wpk pass; depth-2 ring per stream ----
  bf16_t* sbuf = (bf16_t*)smem;
  if (lv) {
#pragma unroll
    for (int r = 0; r < 4; ++r) {
      const int ro = (quad * 4 + r) * 264 + wv * 16 + ln;
      sbuf[ro] = (bf16_t)S1[r];
      sbuf[2112 + ro] = (bf16_t)S2[r];
    }
  }
  __syncthreads();
  f32x4 ac1[4], ac2[4];
#pragma unroll
  for (int i = 0; i < 4; ++i) {
    ac1[i] = (f32x4){0.f, 0.f, 0.f, 0.f};
    ac2[i] = (f32x4){0.f, 0.f, 0.f, 0.f};
  }
  {
    const bf16x8* wp = (const bf16x8*)Wpk + (size_t)(wv * 4) * 8 * 64 + l;
    const bf16_t* s1row = sbuf + (ln & 7) * 264 + quad * 8;  // dup rows 8-15
    const bf16_t* s2row = s1row + 2112;
    bf16x8 wr[4][2];
#pragma unroll
    for (int i = 0; i < 4; ++i) {
      wr[i][0] = wp[i * 512];
      wr[i][1] = wp[i * 512 + 64];
    }
#pragma unroll
    for (int kb = 0; kb < 8; ++kb) {
      const bf16x8 a1 = *(const bf16x8*)(s1row + kb * 32);
      const bf16x8 a2 = *(const bf16x8*)(s2row + kb * 32);
#pragma unroll
      for (int i = 0; i < 4; ++i) {
        const bf16x8 bb = wr[i][kb & 1];
        if (kb < 6) wr[i][kb & 1] = wp[i * 512 + (kb + 2) * 64];
        ac1[i] = MFMA_BF16(a1, bb, ac1[i]);
        ac2[i] = MFMA_BF16(a2, bb, ac2[i]);
      }
    }
  }
  __syncthreads();  // sbuf reads done before fsb overwrite

  // ---- epilogue: closed form, lane-contiguous full-line stores via swizzled LDS ----
  const float sf = (float)s;
  const float c_vf = sf * DTv;
  const float c_xf = sf * sf * DTv * HDT;
  int csw[4];
#pragma unroll
  for (int i = 0; i < 4; ++i) csw[i] = swz((wv * 4 + i) * 16 + ln);
  auto store_chunk = [&](float* __restrict__ dstA, auto vex) {
    if (lv) {
#pragma unroll
      for (int i = 0; i < 4; ++i)
#pragma unroll
        for (int r = 0; r < 4; ++r)
          fsb[(quad * 4 + r) * 1024 + csw[i]] = vex(i, r);
    }
    __syncthreads();
    float* dst_ = dstA + (size_t)row_base * Dn;
#pragma unroll
    for (int k = 0; k < 2; ++k) {
      const int fi = k * 4096 + tid * 4;
      *(f32x4*)(dst_ + fi) = *(const f32x4*)(fsb + (fi >> 10) * 1024 + swz(fi & 1023));
    }
    __syncthreads();
  };
  auto vval = [&](int i, int r) {
    return vs[i][r] + c_vf * (float)fsv[i][r] - HDT * ac1[i][r];
  };
  auto xval = [&](int i, int r) {
    return xs[i][r] + c_vf * vs[i][r] + c_xf * (float)fsv[i][r] - DTv * HDT * ac2[i][r];
  };
  store_chunk(out_v, vval);
  store_chunk(out_x, xval);
}

extern "C" void kernel_launch(void* const* d_in, const int* in_sizes, int n_in,
                              void* d_out, int out_size, void* d_ws, size_t ws_size,
                              hipStream_t stream) {
  const float* x = (const float*)d_in[0];
  const float* v = (const float*)d_in[1];
  const float* force = (const float*)d_in[2];
  const float* U = (const float*)d_in[3];
  const float* W = (const float*)d_in[4];
  const int* steps = (const int*)d_in[5];

  bf16_t* Upk = (bf16_t*)d_ws;                          // 512 KB
  bf16_t* Wpk = (bf16_t*)((char*)d_ws + 512 * 1024);    // 512 KB
  bf16_t* WUpk = (bf16_t*)((char*)d_ws + 1024 * 1024);  // 128 KB

  setup_kernel<<<56, 1024, 0, stream>>>(U, W, Upk, Wpk, WUpk);
  integrate_kernel<<<Bn / BT, 1024, 0, stream>>>(x, v, force, Upk, Wpk, WUpk, steps,
                                                 (float*)d_out);
}

// Round 9
// 153.552 us; speedup vs baseline: 2.4064x; 1.8994x over previous
//
#include <hip/hip_runtime.h>

typedef __bf16 bf16_t;
typedef __bf16 bf16x8 __attribute__((ext_vector_type(8)));
typedef float f32x4 __attribute__((ext_vector_type(4)));

#define MFMA_BF16(a, b, c) __builtin_amdgcn_mfma_f32_16x16x32_bf16((a), (b), (c), 0, 0, 0)

static constexpr int Bn = 4096;
static constexpr int Dn = 1024;
static constexpr int Rn = 256;
static constexpr int BT = 16;
static constexpr float DTv = 0.01f;
static constexpr float HDT = 0.005f;

// XOR-swizzle within a 1024-float row: flips bits [4:2] by bits [7:5]. Bijective,
// preserves 4-float (16B) contiguity, spreads stride-16-float access over bank-slots.
__device__ __forceinline__ int swz(int col) { return col ^ (((col >> 5) & 7) << 2); }

// ---- Fused setup (one launch, 56 blocks x 1024): verified in R5/R8 ----
// blocks 0..31: pack U (kb=b); 32..39: pack W (kb=b-32); 40..55: WU = W@U (m=b-40)
// Upk[((ct*32+kb)*64+l)*8+j] = U[kb*32+(l>>4)*8+j][ct*16+(l&15)]
// Wpk[((ct*8+kb)*64+l)*8+j]  = W[kb*32+(l>>4)*8+j][ct*16+(l&15)]
// WUpk same layout as Wpk for WU[256x256].
__global__ __launch_bounds__(1024)
void setup_kernel(const float* __restrict__ U, const float* __restrict__ W,
                  bf16_t* __restrict__ Upk, bf16_t* __restrict__ Wpk,
                  bf16_t* __restrict__ WUpk) {
  __shared__ __align__(16) char ssm[66816];
  const int tid = (int)threadIdx.x;
  const int b = (int)blockIdx.x;
  const int l = tid & 63;
  const int wv = tid >> 6;
  const int ln = l & 15;
  const int quad = l >> 4;

  if (b < 32) {  // ---- pack U, kb = b ----
    bf16_t* ubuf = (bf16_t*)ssm;  // [32][268]
    const int row = tid >> 5, c0 = (tid & 31) * 8;
    const float* src = U + (size_t)(b * 32 + row) * Rn + c0;
    f32x4 u0 = *(const f32x4*)src;
    f32x4 u1 = *(const f32x4*)(src + 4);
    bf16_t* d = ubuf + row * 268 + c0;
#pragma unroll
    for (int j = 0; j < 4; ++j) { d[j] = (bf16_t)u0[j]; d[4 + j] = (bf16_t)u1[j]; }
    __syncthreads();
    bf16x8 v;
#pragma unroll
    for (int j = 0; j < 8; ++j) v[j] = ubuf[(quad * 8 + j) * 268 + wv * 16 + ln];
    ((bf16x8*)Upk)[(size_t)(wv * 32 + b) * 64 + l] = v;
  } else if (b < 40) {  // ---- pack W, kb = b-32 ----
    const int kb = b - 32;
    bf16_t* wbuf2 = (bf16_t*)ssm;  // [32][1044]
    const int row = tid >> 5, c0 = (tid & 31) * 32;
    const float* src = W + (size_t)(kb * 32 + row) * Dn + c0;
    bf16_t* d = wbuf2 + row * 1044 + c0;
#pragma unroll
    for (int k = 0; k < 8; ++k) {
      f32x4 u = *(const f32x4*)(src + k * 4);
#pragma unroll
      for (int j = 0; j < 4; ++j) d[k * 4 + j] = (bf16_t)u[j];
    }
    __syncthreads();
#pragma unroll
    for (int cc = 0; cc < 4; ++cc) {
      const int ct = wv + cc * 16;
      bf16x8 v;
#pragma unroll
      for (int j = 0; j < 8; ++j) v[j] = wbuf2[(quad * 8 + j) * 1044 + ct * 16 + ln];
      ((bf16x8*)Wpk)[(size_t)(ct * 8 + kb) * 64 + l] = v;
    }
  } else {  // ---- WU = W @ U, rows m*16..+16; 4 independent acc chains (split-K) ----
    const int m = b - 40;
    bf16_t* wbuf = (bf16_t*)ssm;  // [16][1032]
    {
      int row = tid >> 6;
      int c0 = (tid & 63) * 16;
      const float* src = W + (size_t)(m * 16 + row) * Dn + c0;
      bf16_t* dst = wbuf + row * 1032 + c0;
#pragma unroll
      for (int j = 0; j < 16; ++j) dst[j] = (bf16_t)src[j];
    }
    __syncthreads();
    const int ucol = wv * 16 + ln;
    float uf[8][8];
#pragma unroll
    for (int p = 0; p < 8; ++p)
#pragma unroll
      for (int j = 0; j < 8; ++j)
        uf[p][j] = U[(size_t)(p * 32 + quad * 8 + j) * Rn + ucol];
    f32x4 ac[4];
#pragma unroll
    for (int c = 0; c < 4; ++c) ac[c] = (f32x4){0.f, 0.f, 0.f, 0.f};
    const bf16_t* arow = wbuf + ln * 1032 + quad * 8;
#pragma unroll
    for (int kb = 0; kb < 32; ++kb) {
      bf16x8 bb;
#pragma unroll
      for (int j = 0; j < 8; ++j) bb[j] = (bf16_t)uf[kb & 7][j];
      const bf16x8 a = *(const bf16x8*)(arow + kb * 32);
      ac[kb & 3] = MFMA_BF16(a, bb, ac[kb & 3]);
      if (kb < 24) {
#pragma unroll
        for (int j = 0; j < 8; ++j)
          uf[kb & 7][j] = U[(size_t)((kb + 8) * 32 + quad * 8 + j) * Rn + ucol];
      }
    }
    f32x4 acc;
#pragma unroll
    for (int r = 0; r < 4; ++r)
      acc[r] = (ac[0][r] + ac[1][r]) + (ac[2][r] + ac[3][r]);
#pragma unroll
    for (int r = 0; r < 4; ++r) {
      int rw = m * 16 + quad * 4 + r;
      int kb = rw >> 5;
      int sub = (rw >> 3) & 3;
      int j = rw & 7;
      size_t slot = ((size_t)(wv * 8 + kb) * 64 + sub * 16 + ln) * 8 + j;
      WUpk[slot] = (bf16_t)acc[r];
    }
  }
}

// ---- Fused integrator (R4 core, register-feasibility-proven config) ----
//   hv_{h+1} = hv_h + hdt*(FU - T_h@WU),  FU = f@U, WU = W@U
//   v_out = v0 + s*dt*f - hdt*(S1@W),     S1 = sum T_h
//   x_out = x0 + s*dt*v0 + s^2*dt*hdt*f - dt*hdt*(S2@W),  S2 = sum c_h*T_h, c_h = s-ceil(h/2)
// 256 blocks x 1024 thr, 1 block/CU (16 waves x ~112 unified regs == full file).
// R9: early wu/wr prefetch issue (latency under staging barriers); single-pass
// 64KB epilogue restage (4 barriers instead of 8, 16KB store bursts).
__global__ __launch_bounds__(1024)
__attribute__((amdgpu_waves_per_eu(4, 4)))
void integrate_kernel(const float* __restrict__ x_in, const float* __restrict__ v_in,
                      const float* __restrict__ force,
                      const bf16_t* __restrict__ Upk, const bf16_t* __restrict__ Wpk,
                      const bf16_t* __restrict__ WUpk,
                      const int* __restrict__ steps_p, float* __restrict__ out) {
  // union: init abuf[3][16][1032] bf16 (99072B) / loop tbf[2][16][264] bf16
  //        / final sbuf[2][16][264] bf16 / epilogue fsb[16][1024] f32 (64KB)
  __shared__ __align__(16) char smem[99072];
  bf16_t* abuf = (bf16_t*)smem;
  float* fsb = (float*)smem;

  const int tid = (int)threadIdx.x;
  const int wv = tid >> 6;  // 0..15
  const int l = tid & 63;
  const int ln = l & 15;
  const int quad = l >> 4;
  const int s = steps_p[0];
  const int nhalf = 2 * s;
  const int row_base = (int)blockIdx.x * BT;

  float* out_x = out;
  float* out_v = out + (size_t)Bn * Dn;

  float xs[4][4], vs[4][4];  // ORIGINAL x0, v0 (C/D layout)
  bf16_t fsv[4][4];

  // ---- direct C/D loads: 16 lanes x 64B contiguous per instr => line-perfect ----
#pragma unroll
  for (int i = 0; i < 4; ++i) {
    const int col = (wv * 4 + i) * 16 + ln;
#pragma unroll
    for (int r = 0; r < 4; ++r) {
      const size_t g = (size_t)(row_base + quad * 4 + r) * Dn + col;
      xs[i][r] = x_in[g];
      vs[i][r] = v_in[g];
      fsv[i][r] = (bf16_t)force[g];
    }
  }

  // ---- WU fragments (ct = wv): ISSUE EARLY — L2 latency hides under staging ----
  bf16x8 wu[8];
  {
    const bf16x8* wub = (const bf16x8*)WUpk + (size_t)wv * 8 * 64 + l;
#pragma unroll
    for (int kb = 0; kb < 8; ++kb) wu[kb] = wub[kb * 64];
  }

  // ---- stage full-width abuf directly from regs ----
#pragma unroll
  for (int i = 0; i < 4; ++i) {
    const int col = (wv * 4 + i) * 16 + ln;
#pragma unroll
    for (int r = 0; r < 4; ++r) {
      const int ro = (quad * 4 + r) * 1032 + col;
      abuf[ro] = (bf16_t)xs[i][r];
      abuf[16512 + ro] = (bf16_t)vs[i][r];
      abuf[33024 + ro] = fsv[i][r];
    }
  }
  __syncthreads();

  // ---- init: hx0 = x0@U, hv0 = v0@U, FU = f@U; ONE 32-deep Upk pass ----
  f32x4 hx = {0.f, 0.f, 0.f, 0.f};
  f32x4 hv = {0.f, 0.f, 0.f, 0.f};
  f32x4 FU = {0.f, 0.f, 0.f, 0.f};
  {
    const bf16x8* up = (const bf16x8*)Upk + (size_t)wv * 32 * 64 + l;
    const bf16_t* ax = abuf + ln * 1032 + quad * 8;
    bf16x8 ur[8];
#pragma unroll
    for (int p = 0; p < 8; ++p) ur[p] = up[p * 64];
#pragma unroll
    for (int kb = 0; kb < 32; ++kb) {
      const bf16x8 bb = ur[kb & 7];
      if (kb < 24) ur[kb & 7] = up[(kb + 8) * 64];
      const bf16x8 a0 = *(const bf16x8*)(ax + kb * 32);
      const bf16x8 a1 = *(const bf16x8*)(ax + 16512 + kb * 32);
      const bf16x8 a2 = *(const bf16x8*)(ax + 33024 + kb * 32);
      hx = MFMA_BF16(a0, bb, hx);
      hv = MFMA_BF16(a1, bb, hv);
      FU = MFMA_BF16(a2, bb, FU);
    }
  }
  __syncthreads();  // abuf dead

  // ---- R-space loop: zero global traffic; dbuf T, 1 barrier/half-step ----
  f32x4 S1 = {0.f, 0.f, 0.f, 0.f};
  f32x4 S2 = {0.f, 0.f, 0.f, 0.f};
  bf16_t* tbase = (bf16_t*)smem;
  for (int h = 0; h < nhalf; ++h) {
    if (h & 1) {
#pragma unroll
      for (int r = 0; r < 4; ++r) hx[r] += DTv * hv[r];
    }
    const float ch = (float)(s - ((h + 1) >> 1));
    bf16_t* tb = tbase + (h & 1) * 4224;
#pragma unroll
    for (int r = 0; r < 4; ++r) {
      float a = fminf(fmaxf(hx[r], -15.f), 15.f);
      const float e = __expf(2.f * a);
      const float gate = 1.f - 2.f * __builtin_amdgcn_rcpf(e + 1.f);  // tanh(a)
      const float t = gate * hv[r] * hv[r];
      S1[r] += t;
      S2[r] += ch * t;
      tb[(quad * 4 + r) * 264 + wv * 16 + ln] = (bf16_t)t;
    }
    __syncthreads();
    f32x4 g0 = {0.f, 0.f, 0.f, 0.f};
    f32x4 g1 = {0.f, 0.f, 0.f, 0.f};
    f32x4 g2 = {0.f, 0.f, 0.f, 0.f};
    f32x4 g3 = {0.f, 0.f, 0.f, 0.f};
    const bf16_t* trow = tb + ln * 264 + quad * 8;
    g0 = MFMA_BF16(*(const bf16x8*)(trow + 0 * 32), wu[0], g0);
    g1 = MFMA_BF16(*(const bf16x8*)(trow + 1 * 32), wu[1], g1);
    g2 = MFMA_BF16(*(const bf16x8*)(trow + 2 * 32), wu[2], g2);
    g3 = MFMA_BF16(*(const bf16x8*)(trow + 3 * 32), wu[3], g3);
    g0 = MFMA_BF16(*(const bf16x8*)(trow + 4 * 32), wu[4], g0);
    g1 = MFMA_BF16(*(const bf16x8*)(trow + 5 * 32), wu[5], g1);
    g2 = MFMA_BF16(*(const bf16x8*)(trow + 6 * 32), wu[6], g2);
    g3 = MFMA_BF16(*(const bf16x8*)(trow + 7 * 32), wu[7], g3);
#pragma unroll
    for (int r = 0; r < 4; ++r)
      hv[r] += HDT * (FU[r] - ((g0[r] + g1[r]) + (g2[r] + g3[r])));
    // no second barrier: next iteration writes the OTHER buffer
  }
  __syncthreads();  // all T reads done before sbuf overwrite

  // ---- final: G1 = S1@W, G2 = S2@W, one Wpk pass; depth-2 ring per stream ----
  bf16_t* sbuf = (bf16_t*)smem;
  const bf16x8* wp = (const bf16x8*)Wpk + (size_t)(wv * 4) * 8 * 64 + l;
  bf16x8 wr[4][2];
#pragma unroll
  for (int i = 0; i < 4; ++i) {  // prefetch ISSUED BEFORE sbuf staging: latency hidden
    wr[i][0] = wp[i * 512];
    wr[i][1] = wp[i * 512 + 64];
  }
#pragma unroll
  for (int r = 0; r < 4; ++r) {
    const int ro = (quad * 4 + r) * 264 + wv * 16 + ln;
    sbuf[ro] = (bf16_t)S1[r];
    sbuf[4224 + ro] = (bf16_t)S2[r];
  }
  __syncthreads();
  f32x4 ac1[4], ac2[4];
#pragma unroll
  for (int i = 0; i < 4; ++i) {
    ac1[i] = (f32x4){0.f, 0.f, 0.f, 0.f};
    ac2[i] = (f32x4){0.f, 0.f, 0.f, 0.f};
  }
  {
    const bf16_t* s1row = sbuf + ln * 264 + quad * 8;
    const bf16_t* s2row = s1row + 4224;
#pragma unroll
    for (int kb = 0; kb < 8; ++kb) {
      const bf16x8 a1 = *(const bf16x8*)(s1row + kb * 32);
      const bf16x8 a2 = *(const bf16x8*)(s2row + kb * 32);
#pragma unroll
      for (int i = 0; i < 4; ++i) {
        const bf16x8 bb = wr[i][kb & 1];
        if (kb < 6) wr[i][kb & 1] = wp[i * 512 + (kb + 2) * 64];
        ac1[i] = MFMA_BF16(a1, bb, ac1[i]);
        ac2[i] = MFMA_BF16(a2, bb, ac2[i]);
      }
    }
  }
  __syncthreads();  // sbuf reads done before fsb overwrite

  // ---- epilogue: closed form; single 64KB restage per output, 16KB store bursts ----
  const float sf = (float)s;
  const float c_vf = sf * DTv;
  const float c_xf = sf * sf * DTv * HDT;
  int csw[4];
#pragma unroll
  for (int i = 0; i < 4; ++i) csw[i] = swz((wv * 4 + i) * 16 + ln);
  auto store_all = [&](float* __restrict__ dstA, auto vex) {
    // every thread writes all 16 of its values (16 rows covered across quads)
#pragma unroll
    for (int i = 0; i < 4; ++i)
#pragma unroll
      for (int r = 0; r < 4; ++r)
        fsb[(quad * 4 + r) * 1024 + csw[i]] = vex(i, r);
    __syncthreads();
    float* dst_ = dstA + (size_t)row_base * Dn;
#pragma unroll
    for (int k = 0; k < 4; ++k) {
      const int fi = k * 4096 + tid * 4;  // row = fi>>10, col = fi&1023
      *(f32x4*)(dst_ + fi) = *(const f32x4*)(fsb + (fi >> 10) * 1024 + swz(fi & 1023));
    }
    __syncthreads();
  };
  auto vval = [&](int i, int r) {
    return vs[i][r] + c_vf * (float)fsv[i][r] - HDT * ac1[i][r];
  };
  auto xval = [&](int i, int r) {
    return xs[i][r] + c_vf * vs[i][r] + c_xf * (float)fsv[i][r] - DTv * HDT * ac2[i][r];
  };
  store_all(out_v, vval);
  store_all(out_x, xval);
}

extern "C" void kernel_launch(void* const* d_in, const int* in_sizes, int n_in,
                              void* d_out, int out_size, void* d_ws, size_t ws_size,
                              hipStream_t stream) {
  const float* x = (const float*)d_in[0];
  const float* v = (const float*)d_in[1];
  const float* force = (const float*)d_in[2];
  const float* U = (const float*)d_in[3];
  const float* W = (const float*)d_in[4];
  const int* steps = (const int*)d_in[5];

  bf16_t* Upk = (bf16_t*)d_ws;                          // 512 KB
  bf16_t* Wpk = (bf16_t*)((char*)d_ws + 512 * 1024);    // 512 KB
  bf16_t* WUpk = (bf16_t*)((char*)d_ws + 1024 * 1024);  // 128 KB

  setup_kernel<<<56, 1024, 0, stream>>>(U, W, Upk, Wpk, WUpk);
  integrate_kernel<<<Bn / BT, 1024, 0, stream>>>(x, v, force, Upk, Wpk, WUpk, steps,
                                                 (float*)d_out);
}